// Round 1
// baseline (1139.168 us; speedup 1.0000x reference)
//
#include <hip/hip_runtime.h>
#include <hip/hip_bf16.h>

// Problem sizes (from reference): N=100000 nodes, 64 in-feats, 32 hidden,
// E=3200000 edges per edge type, scalar output per node.

__global__ void deg_kernel(const int* __restrict__ ei_n, const int* __restrict__ ei_s,
                           float* __restrict__ deg_n, float* __restrict__ deg_s,
                           int En, int Es) {
    int gid = blockIdx.x * blockDim.x + threadIdx.x;
    if (gid < En) {
        atomicAdd(&deg_n[ei_n[En + gid]], 1.0f);          // dst row of edge_index
    } else if (gid < En + Es) {
        int e = gid - En;
        atomicAdd(&deg_s[ei_s[Es + e]], 1.0f);
    }
}

__global__ void dinv_kernel(float* __restrict__ deg_n, float* __restrict__ deg_s, int n) {
    int i = blockIdx.x * blockDim.x + threadIdx.x;
    if (i < n) {
        deg_n[i] = rsqrtf(deg_n[i] + 1.0f);               // +1 = self-loop
        deg_s[i] = rsqrtf(deg_s[i] + 1.0f);
    }
}

// xws = (x @ W) * dinv  (per node row), for both edge types; acc seeded = xws
// (self-loop message, pre-scaled by dinv[src]; final dinv[dst] applied later).
__global__ void xw_kernel(const float* __restrict__ x,
                          const float* __restrict__ Wn, const float* __restrict__ Ws,
                          const float* __restrict__ dinv_n, const float* __restrict__ dinv_s,
                          float* __restrict__ xws_n, float* __restrict__ xws_s,
                          float* __restrict__ acc_n, float* __restrict__ acc_s,
                          int n_nodes) {
    __shared__ float wn[64 * 32];
    __shared__ float wsm[64 * 32];
    for (int i = threadIdx.x; i < 64 * 32; i += blockDim.x) {
        wn[i] = Wn[i];
        wsm[i] = Ws[i];
    }
    __syncthreads();
    int lane = threadIdx.x & 31;
    int nodes_per_block = blockDim.x >> 5;
    int node = blockIdx.x * nodes_per_block + (threadIdx.x >> 5);
    if (node >= n_nodes) return;

    const float4* x4 = (const float4*)(x + (size_t)node * 64);
    float an = 0.f, as = 0.f;
#pragma unroll
    for (int k4 = 0; k4 < 16; ++k4) {
        float4 xv = x4[k4];
        int k = k4 * 4;
        an += xv.x * wn[(k + 0) * 32 + lane] + xv.y * wn[(k + 1) * 32 + lane]
            + xv.z * wn[(k + 2) * 32 + lane] + xv.w * wn[(k + 3) * 32 + lane];
        as += xv.x * wsm[(k + 0) * 32 + lane] + xv.y * wsm[(k + 1) * 32 + lane]
            + xv.z * wsm[(k + 2) * 32 + lane] + xv.w * wsm[(k + 3) * 32 + lane];
    }
    float vn = an * dinv_n[node];
    float vs = as * dinv_s[node];
    size_t o = (size_t)node * 32 + lane;
    xws_n[o] = vn;
    acc_n[o] = vn;
    xws_s[o] = vs;
    acc_s[o] = vs;
}

// Per edge: 32 lanes gather xws[src] and atomically add into acc[dst].
__global__ void scatter_kernel(const int* __restrict__ ei_n, const int* __restrict__ ei_s,
                               const float* __restrict__ xws_n, const float* __restrict__ xws_s,
                               float* __restrict__ acc_n, float* __restrict__ acc_s,
                               int En, int Es) {
    unsigned int gid = blockIdx.x * blockDim.x + threadIdx.x;
    unsigned int e = gid >> 5;
    int f = gid & 31;
    const int* ei;
    const float* xws;
    float* acc;
    int E;
    if (e < (unsigned)En) {
        ei = ei_n; xws = xws_n; acc = acc_n; E = En;
    } else if (e < (unsigned)(En + Es)) {
        e -= En;
        ei = ei_s; xws = xws_s; acc = acc_s; E = Es;
    } else {
        return;
    }
    int src = ei[e];
    int dst = ei[E + e];
    atomicAdd(&acc[(size_t)dst * 32 + f], xws[(size_t)src * 32 + f]);
}

// out[d] = sum_f relu(dinv_n*acc_n + b_n + dinv_s*acc_s + b_s) * W_lin[f] + b_lin
__global__ void final_kernel(const float* __restrict__ acc_n, const float* __restrict__ acc_s,
                             const float* __restrict__ dinv_n, const float* __restrict__ dinv_s,
                             const float* __restrict__ b_n, const float* __restrict__ b_s,
                             const float* __restrict__ W_lin, const float* __restrict__ b_lin,
                             float* __restrict__ out, int n_nodes) {
    int gid = blockIdx.x * blockDim.x + threadIdx.x;
    int node = gid >> 5;
    int f = gid & 31;
    if (node >= n_nodes) return;
    size_t o = (size_t)node * 32 + f;
    float v = dinv_n[node] * acc_n[o] + b_n[f] + dinv_s[node] * acc_s[o] + b_s[f];
    v = fmaxf(v, 0.f);
    v *= W_lin[f];
#pragma unroll
    for (int off = 16; off > 0; off >>= 1) v += __shfl_xor(v, off);
    if (f == 0) out[node] = v + b_lin[0];
}

extern "C" void kernel_launch(void* const* d_in, const int* in_sizes, int n_in,
                              void* d_out, int out_size, void* d_ws, size_t ws_size,
                              hipStream_t stream) {
    const float* x     = (const float*)d_in[0];
    const int*   ei_n  = (const int*)d_in[1];
    const int*   ei_s  = (const int*)d_in[2];
    const float* W_n   = (const float*)d_in[3];
    const float* b_n   = (const float*)d_in[4];
    const float* W_s   = (const float*)d_in[5];
    const float* b_s   = (const float*)d_in[6];
    const float* W_lin = (const float*)d_in[7];
    const float* b_lin = (const float*)d_in[8];
    float* out = (float*)d_out;

    const int N  = in_sizes[0] / 64;   // 100000
    const int En = in_sizes[1] / 2;    // 3200000
    const int Es = in_sizes[2] / 2;    // 3200000

    float* ws    = (float*)d_ws;
    float* deg_n = ws;                       // N (becomes dinv_n)
    float* deg_s = ws + (size_t)N;           // N (becomes dinv_s)
    float* xws_n = ws + 2 * (size_t)N;       // 32N
    float* xws_s = xws_n + 32 * (size_t)N;   // 32N
    float* acc_n = xws_s + 32 * (size_t)N;   // 32N
    float* acc_s = acc_n + 32 * (size_t)N;   // 32N  (total 130N floats = 52 MB)

    hipMemsetAsync(deg_n, 0, 2 * (size_t)N * sizeof(float), stream);

    {
        int total = En + Es;
        deg_kernel<<<(total + 255) / 256, 256, 0, stream>>>(ei_n, ei_s, deg_n, deg_s, En, Es);
    }
    dinv_kernel<<<(N + 255) / 256, 256, 0, stream>>>(deg_n, deg_s, N);

    {
        int nodes_per_block = 256 / 32;  // 8
        int blocks = (N + nodes_per_block - 1) / nodes_per_block;
        xw_kernel<<<blocks, 256, 0, stream>>>(x, W_n, W_s, deg_n, deg_s,
                                              xws_n, xws_s, acc_n, acc_s, N);
    }
    {
        size_t total_threads = (size_t)(En + Es) * 32;
        int blocks = (int)((total_threads + 255) / 256);
        scatter_kernel<<<blocks, 256, 0, stream>>>(ei_n, ei_s, xws_n, xws_s, acc_n, acc_s, En, Es);
    }
    {
        size_t total_threads = (size_t)N * 32;
        int blocks = (int)((total_threads + 255) / 256);
        final_kernel<<<blocks, 256, 0, stream>>>(acc_n, acc_s, deg_n, deg_s,
                                                 b_n, b_s, W_lin, b_lin, out, N);
    }
}

// Round 2
// 1110.314 us; speedup vs baseline: 1.0260x; 1.0260x over previous
//
#include <hip/hip_runtime.h>
#include <hip/hip_bf16.h>

// N=100000 nodes, 64 in-feats, 32 hidden, E=3200000 edges per type.
// Strategy: CSR build (count/scan/bin, int atomics only) + fused pull-gather
// reduce. Eliminates the 204.8M float atomics (L2 atomic-throughput ceiling,
// 662us in round 1).

#define SCAN_BLOCK 1024

// --- Phase 1: count in-degrees (both edge types) with int atomics ---
__global__ void count_kernel(const int* __restrict__ ei_n, const int* __restrict__ ei_s,
                             int* __restrict__ arr, int N, int En, int Es) {
    int gid = blockIdx.x * blockDim.x + threadIdx.x;
    if (gid < En) {
        atomicAdd(&arr[ei_n[En + gid]], 1);
    } else if (gid < En + Es) {
        int e = gid - En;
        atomicAdd(&arr[N + ei_s[Es + e]], 1);
    }
}

// --- dinv = rsqrt(count + 1) for both types (arr still holds raw counts) ---
__global__ void dinv_kernel(const int* __restrict__ arr, float* __restrict__ dinv, int M) {
    int i = blockIdx.x * blockDim.x + threadIdx.x;
    if (i < M) dinv[i] = rsqrtf((float)arr[i] + 1.0f);
}

// --- Hierarchical inclusive scan over arr[0..M) ---
__global__ void scan1_kernel(int* __restrict__ arr, int* __restrict__ bsum, int M) {
    __shared__ int s[SCAN_BLOCK];
    int i = blockIdx.x * SCAN_BLOCK + threadIdx.x;
    s[threadIdx.x] = (i < M) ? arr[i] : 0;
    __syncthreads();
#pragma unroll
    for (int off = 1; off < SCAN_BLOCK; off <<= 1) {
        int t = (threadIdx.x >= off) ? s[threadIdx.x - off] : 0;
        __syncthreads();
        s[threadIdx.x] += t;
        __syncthreads();
    }
    if (i < M) arr[i] = s[threadIdx.x];
    if (threadIdx.x == SCAN_BLOCK - 1) bsum[blockIdx.x] = s[SCAN_BLOCK - 1];
}

__global__ void scan2_kernel(int* __restrict__ bsum, int nb) {
    __shared__ int s[SCAN_BLOCK];
    s[threadIdx.x] = (threadIdx.x < nb) ? bsum[threadIdx.x] : 0;
    __syncthreads();
#pragma unroll
    for (int off = 1; off < SCAN_BLOCK; off <<= 1) {
        int t = (threadIdx.x >= off) ? s[threadIdx.x - off] : 0;
        __syncthreads();
        s[threadIdx.x] += t;
        __syncthreads();
    }
    if (threadIdx.x < nb) bsum[threadIdx.x] = s[threadIdx.x];
}

__global__ void scan3_kernel(int* __restrict__ arr, const int* __restrict__ bsum, int M) {
    int i = blockIdx.x * SCAN_BLOCK + threadIdx.x;
    if (blockIdx.x > 0 && i < M) arr[i] += bsum[blockIdx.x - 1];
}

// --- xws = (x @ W) * dinv[node] for both types ---
__global__ void xw_kernel(const float* __restrict__ x,
                          const float* __restrict__ Wn, const float* __restrict__ Ws,
                          const float* __restrict__ dinv,
                          float* __restrict__ xws_n, float* __restrict__ xws_s,
                          int n_nodes) {
    __shared__ float wn[64 * 32];
    __shared__ float wsm[64 * 32];
    for (int i = threadIdx.x; i < 64 * 32; i += blockDim.x) {
        wn[i] = Wn[i];
        wsm[i] = Ws[i];
    }
    __syncthreads();
    int lane = threadIdx.x & 31;
    int node = blockIdx.x * (blockDim.x >> 5) + (threadIdx.x >> 5);
    if (node >= n_nodes) return;

    const float4* x4 = (const float4*)(x + (size_t)node * 64);
    float an = 0.f, as = 0.f;
#pragma unroll
    for (int k4 = 0; k4 < 16; ++k4) {
        float4 xv = x4[k4];
        int k = k4 * 4;
        an += xv.x * wn[(k + 0) * 32 + lane] + xv.y * wn[(k + 1) * 32 + lane]
            + xv.z * wn[(k + 2) * 32 + lane] + xv.w * wn[(k + 3) * 32 + lane];
        as += xv.x * wsm[(k + 0) * 32 + lane] + xv.y * wsm[(k + 1) * 32 + lane]
            + xv.z * wsm[(k + 2) * 32 + lane] + xv.w * wsm[(k + 3) * 32 + lane];
    }
    size_t o = (size_t)node * 32 + lane;
    xws_n[o] = an * dinv[node];
    xws_s[o] = as * dinv[n_nodes + node];
}

// --- Bin edges: atomicSub on inclusive offsets -> adj; arr becomes exclusive ---
__global__ void bin_kernel(const int* __restrict__ ei_n, const int* __restrict__ ei_s,
                           int* __restrict__ arr, int* __restrict__ adj,
                           int N, int En, int Es) {
    int gid = blockIdx.x * blockDim.x + threadIdx.x;
    if (gid < En) {
        int src = ei_n[gid];
        int dst = ei_n[En + gid];
        int pos = atomicSub(&arr[dst], 1) - 1;
        adj[pos] = src;
    } else if (gid < En + Es) {
        int e = gid - En;
        int src = ei_s[e];
        int dst = ei_s[Es + e];
        int pos = atomicSub(&arr[N + dst], 1) - 1;
        adj[pos] = src;
    }
}

// --- Fused gather-reduce + epilogue: 32 lanes per node ---
__global__ void reduce_kernel(const int* __restrict__ arr, const int* __restrict__ adj,
                              const float* __restrict__ xws_n, const float* __restrict__ xws_s,
                              const float* __restrict__ dinv,
                              const float* __restrict__ b_n, const float* __restrict__ b_s,
                              const float* __restrict__ W_lin, const float* __restrict__ b_lin,
                              float* __restrict__ out, int N, int Etot) {
    int gid = blockIdx.x * blockDim.x + threadIdx.x;
    int node = gid >> 5;
    int f = gid & 31;
    if (node >= N) return;

    // near: bucket [arr[node], arr[node+1]); arr[N] is similar's first offset (=En), valid.
    int s0 = arr[node];
    int e0 = arr[node + 1];
    float vn = xws_n[(size_t)node * 32 + f];   // self-loop term
    int j = s0;
    for (; j + 4 <= e0; j += 4) {
        int a0 = adj[j], a1 = adj[j + 1], a2 = adj[j + 2], a3 = adj[j + 3];
        float g0 = xws_n[(size_t)a0 * 32 + f];
        float g1 = xws_n[(size_t)a1 * 32 + f];
        float g2 = xws_n[(size_t)a2 * 32 + f];
        float g3 = xws_n[(size_t)a3 * 32 + f];
        vn += g0 + g1 + g2 + g3;
    }
    for (; j < e0; ++j) vn += xws_n[(size_t)adj[j] * 32 + f];

    // similar: bucket [arr[N+node], end)
    int s1 = arr[N + node];
    int e1 = (node == N - 1) ? Etot : arr[N + node + 1];
    float vs = xws_s[(size_t)node * 32 + f];
    j = s1;
    for (; j + 4 <= e1; j += 4) {
        int a0 = adj[j], a1 = adj[j + 1], a2 = adj[j + 2], a3 = adj[j + 3];
        float g0 = xws_s[(size_t)a0 * 32 + f];
        float g1 = xws_s[(size_t)a1 * 32 + f];
        float g2 = xws_s[(size_t)a2 * 32 + f];
        float g3 = xws_s[(size_t)a3 * 32 + f];
        vs += g0 + g1 + g2 + g3;
    }
    for (; j < e1; ++j) vs += xws_s[(size_t)adj[j] * 32 + f];

    float h = vn * dinv[node] + b_n[f] + vs * dinv[N + node] + b_s[f];
    h = fmaxf(h, 0.f);
    float p = h * W_lin[f];
#pragma unroll
    for (int off = 16; off > 0; off >>= 1) p += __shfl_xor(p, off);
    if (f == 0) out[node] = p + b_lin[0];
}

extern "C" void kernel_launch(void* const* d_in, const int* in_sizes, int n_in,
                              void* d_out, int out_size, void* d_ws, size_t ws_size,
                              hipStream_t stream) {
    const float* x     = (const float*)d_in[0];
    const int*   ei_n  = (const int*)d_in[1];
    const int*   ei_s  = (const int*)d_in[2];
    const float* W_n   = (const float*)d_in[3];
    const float* b_n   = (const float*)d_in[4];
    const float* W_s   = (const float*)d_in[5];
    const float* b_s   = (const float*)d_in[6];
    const float* W_lin = (const float*)d_in[7];
    const float* b_lin = (const float*)d_in[8];
    float* out = (float*)d_out;

    const int N    = in_sizes[0] / 64;   // 100000
    const int En   = in_sizes[1] / 2;    // 3200000
    const int Es   = in_sizes[2] / 2;    // 3200000
    const int Etot = En + Es;
    const int M    = 2 * N;              // combined count/offset array length

    // Workspace layout (4-byte words):
    // arr[2N] | bsum[1024] | dinv[2N] | xws_n[32N] | xws_s[32N] | adj[En+Es]
    int*   arr   = (int*)d_ws;
    int*   bsum  = arr + (size_t)M;
    float* dinv  = (float*)(bsum + 1024);
    float* xws_n = dinv + (size_t)M;
    float* xws_s = xws_n + (size_t)32 * N;
    int*   adj   = (int*)(xws_s + (size_t)32 * N);

    hipMemsetAsync(arr, 0, (size_t)M * sizeof(int), stream);

    count_kernel<<<(Etot + 255) / 256, 256, 0, stream>>>(ei_n, ei_s, arr, N, En, Es);
    dinv_kernel<<<(M + 255) / 256, 256, 0, stream>>>(arr, dinv, M);

    int nb = (M + SCAN_BLOCK - 1) / SCAN_BLOCK;  // 196
    scan1_kernel<<<nb, SCAN_BLOCK, 0, stream>>>(arr, bsum, M);
    scan2_kernel<<<1, SCAN_BLOCK, 0, stream>>>(bsum, nb);
    scan3_kernel<<<nb, SCAN_BLOCK, 0, stream>>>(arr, bsum, M);

    {
        int blocks = (N + 7) / 8;  // 8 nodes per 256-thread block
        xw_kernel<<<blocks, 256, 0, stream>>>(x, W_n, W_s, dinv, xws_n, xws_s, N);
    }
    bin_kernel<<<(Etot + 255) / 256, 256, 0, stream>>>(ei_n, ei_s, arr, adj, N, En, Es);
    {
        int blocks = (int)(((size_t)N * 32 + 255) / 256);
        reduce_kernel<<<blocks, 256, 0, stream>>>(arr, adj, xws_n, xws_s, dinv,
                                                  b_n, b_s, W_lin, b_lin, out, N, Etot);
    }
}